// Round 7
// baseline (2684.051 us; speedup 1.0000x reference)
//
#include <hip/hip_runtime.h>
#include <hip/hip_bf16.h>
#include <math.h>

#define H_ 200
#define W_ 272
#define C_ 256
#define HW 54400
#define NANCH 489600
#define PRE_N 6000
#define POST_N 1000
#define NWORDS 94    // ceil(6000/64)
#define CHUNK_W 1360 // 4 ic * 10 rows * 34 cols halo

// ---- workspace layout (bytes) ----
#define X_OFF       0ull                 // 256*54400*4 = 55,705,600
#define CONF_OFF    55705600ull          // 489600*4   =  1,958,400
#define HIST1_OFF   57664000ull          // 65536*4    =    262,144
#define HIST2_OFF   57926144ull          // 65536*4    =    262,144
#define SCAL_OFF    58188288ull          // 64*4
#define SEL_OFF     58188544ull          // 8192*8     =     65,536
#define TOPIDX_OFF  58254080ull          // 6000*4
#define BOXES_OFF   58278080ull          // 6000*4*4
#define VALID_OFF   58374080ull          // 6000*4
#define MASK_OFF    58398080ull          // 6000*94*8  =  4,512,000
#define W1R_OFF     62910080ull          // [32][256][9][8]*4 = 2,359,296
#define WCR_OFF     65269376ull          // 9*256*4

__device__ __forceinline__ unsigned fkey(float fv) {
    unsigned u = __float_as_uint(fv);
    return (u & 0x80000000u) ? ~u : (u | 0x80000000u);  // monotone: bigger float -> bigger key
}

// ---- clear histograms + repack weights, one launch ----
// w1r layout: [wg=oc>>3][ic][k][oc&7] -> per-wave (ic) weights are 72 contiguous
// floats, wave-uniform address -> s_load into SGPRs.
__global__ __launch_bounds__(256) void k_init(const float* __restrict__ w1,
                                              const float* __restrict__ wcls,
                                              unsigned* __restrict__ hist1,
                                              float* __restrict__ w1r,
                                              float* __restrict__ wcr) {
    int e = blockIdx.x * 256 + threadIdx.x;
    if (e < 131136) hist1[e] = 0u;
    int e1 = e - 131136;
    if (e1 >= 0 && e1 < 589824) {
        int oc = e1 / 2304; int rem = e1 % 2304; int ic = rem / 9; int k = rem % 9;
        int wg = oc >> 3, o = oc & 7;
        w1r[(((size_t)wg * 256 + ic) * 9 + k) * 8 + o] = w1[e1];
    } else if (e1 >= 589824 && e1 < 589824 + 2304) {
        int e2 = e1 - 589824; int a = e2 / 256; int c = e2 % 256;
        wcr[c * 9 + a] = wcls[e2];
    }
}

// ---- 3x3 conv + bias + relu. SGPR-weight conv, 4-ic double-buffered LDS. ----
// Block: 32x * 8y spatial, 4 waves x 8oc. Thread: 4x * 8oc (32 acc VGPRs).
// LDS = 2 x 5.76 KB = 11.5 KB -> residency capped by wave slots (8 blocks/CU),
// not LDS. Weights: wave-uniform s_load -> v_fma_f32 SGPR operand.
// Input: stride-36 LDS rows, explicit float4+float2 reads (structural 8-cycle
// b128 service; not a conflict loss - R5/R6 A/B). One barrier per 4-ic chunk.
// FMA order per accumulator: ic sequential -> ky -> kx (bitwise-stable R1-R6).
__global__ __launch_bounds__(256) void k_conv1(const float* __restrict__ f,
                                               const float* __restrict__ w1r,
                                               const float* __restrict__ b1,
                                               float* __restrict__ xo) {
    __shared__ __align__(16) float sI[2][1440];   // 2 x 5,760 B
    int tid = threadIdx.x;
    int lane = tid & 63;
    int wgl = __builtin_amdgcn_readfirstlane(tid >> 6);  // wave id 0..3 (uniform)
    int xg = lane & 7;            // 8 x-subtiles of 4
    int yg = lane >> 3;           // 8 rows
    int X0 = blockIdx.x * 32;
    int Y0 = blockIdx.y * 8;
    int wg = blockIdx.z * 4 + wgl;   // oc-group of 8 (0..31), wave-uniform
    int y = Y0 + yg;                 // 200 % 8 == 0 -> always valid
    int xbase = X0 + xg * 4;

    // staging slot precompute (loop-invariant across chunks): 1360 words, 6 slots
    int off[6]; int lds[6]; bool ok[6];
#pragma unroll
    for (int it = 0; it < 6; it++) {
        int l = tid + it * 256;
        int ci = l / 340; int r = l - ci * 340; int ry = r / 34; int rx = r - ry * 34;
        int gx = X0 - 1 + rx, gy = Y0 - 1 + ry;
        ok[it] = (l < CHUNK_W) && gx >= 0 && gx < W_ && gy >= 0 && gy < H_;
        off[it] = ci * HW + gy * W_ + gx;
        lds[it] = (ci * 10 + ry) * 36 + rx;
    }
    float rbuf[6];
#pragma unroll
    for (int it = 0; it < 6; it++)
        rbuf[it] = ok[it] ? f[off[it]] : 0.f;       // prefetch chunk 0
#pragma unroll
    for (int it = 0; it < 6; it++)
        if (tid + it * 256 < CHUNK_W) sI[0][lds[it]] = rbuf[it];
    __syncthreads();

    float acc[8][4];
#pragma unroll
    for (int o = 0; o < 8; o++)
#pragma unroll
        for (int i = 0; i < 4; i++) acc[o][i] = 0.f;

    const float* wbase = w1r + (size_t)wg * 256 * 72;

    int cur = 0;
    for (int ic0 = 0; ic0 < 256; ic0 += 4) {
        // issue next chunk's global loads before compute (latency overlaps FMAs)
        if (ic0 < 252) {
            const float* fn = f + (size_t)(ic0 + 4) * HW;
#pragma unroll
            for (int it = 0; it < 6; it++)
                rbuf[it] = ok[it] ? fn[off[it]] : 0.f;
        }
        const float* sbuf = sI[cur];
        for (int ci = 0; ci < 4; ci++) {
            const float* wp = wbase + (size_t)(ic0 + ci) * 72;  // wave-uniform -> SGPR
#pragma unroll
            for (int ky = 0; ky < 3; ky++) {
                const float* irow = &sbuf[(ci * 10 + yg + ky) * 36 + xg * 4];
                float4 va = *(const float4*)irow;          // ds_read_b128
                float2 vb = *(const float2*)(irow + 4);    // ds_read_b64
                float in[6] = {va.x, va.y, va.z, va.w, vb.x, vb.y};
                const float* wrow = wp + ky * 24;   // [kx][8]
#pragma unroll
                for (int kx = 0; kx < 3; kx++) {
#pragma unroll
                    for (int o = 0; o < 8; o++) {
                        float w = wrow[kx * 8 + o];   // SGPR operand
#pragma unroll
                        for (int i = 0; i < 4; i++)
                            acc[o][i] = fmaf(w, in[i + kx], acc[o][i]);
                    }
                }
            }
        }
        // stage next chunk into the other buffer, single barrier per chunk
        if (ic0 < 252) {
#pragma unroll
            for (int it = 0; it < 6; it++)
                if (tid + it * 256 < CHUNK_W) sI[cur ^ 1][lds[it]] = rbuf[it];
        }
        __syncthreads();
        cur ^= 1;
    }
    // epilogue: bias + relu + store (x may exceed 271 on last x-tile)
#pragma unroll
    for (int o = 0; o < 8; o++) {
        int oc = wg * 8 + o;
        float bv = b1[oc];
        float* orow = xo + (size_t)oc * HW + y * W_ + xbase;
        float v0 = fmaxf(acc[o][0] + bv, 0.f), v1 = fmaxf(acc[o][1] + bv, 0.f);
        float v2 = fmaxf(acc[o][2] + bv, 0.f), v3 = fmaxf(acc[o][3] + bv, 0.f);
        if (xbase + 3 < W_) {
            *(float4*)orow = make_float4(v0, v1, v2, v3);
        } else {
            float vv[4] = {v0, v1, v2, v3};
            for (int i = 0; i < 4; i++)
                if (xbase + i < W_) orow[i] = vv[i];
        }
    }
}

// ---- 1x1 cls conv -> conf[p*9+a], fused radix histogram pass 1 ----
__global__ __launch_bounds__(256) void k_cls(const float* __restrict__ x,
                                             const float* __restrict__ wcr,
                                             const float* __restrict__ bc,
                                             float* __restrict__ conf,
                                             unsigned* __restrict__ hist) {
    int p = blockIdx.x * 256 + threadIdx.x;
    if (p >= HW) return;
    float acc[9];
#pragma unroll
    for (int a = 0; a < 9; a++) acc[a] = 0.f;
    for (int c = 0; c < 256; c++) {
        float xv = x[c * HW + p];
        const float* wp = wcr + c * 9;  // uniform -> s_load
#pragma unroll
        for (int a = 0; a < 9; a++) acc[a] = fmaf(wp[a], xv, acc[a]);
    }
#pragma unroll
    for (int a = 0; a < 9; a++) {
        float v = acc[a] + bc[a];
        conf[p * 9 + a] = v;
        atomicAdd(&hist[fkey(v) >> 16], 1u);
    }
}

__global__ __launch_bounds__(256) void k_hist2(const float* __restrict__ conf,
                                               const unsigned* __restrict__ scal, unsigned* hist) {
    int n = blockIdx.x * 256 + threadIdx.x;
    if (n >= NANCH) return;
    unsigned key = fkey(conf[n]);
    if ((key >> 16) == scal[0]) atomicAdd(&hist[key & 0xFFFFu], 1u);
}

// ---- descending scan of 65536-bin histogram, find bin of the target-th largest ----
__global__ __launch_bounds__(1024) void k_scan(const unsigned* __restrict__ hist,
                                               unsigned* scal, int mode) {
    __shared__ unsigned ssum[1024];
    int t = threadIdx.x;
    unsigned target = 6000u - (mode ? scal[1] : 0u);
    int base = 65535 - t * 64;
    // 64 consecutive bins [base-63, base]: 16 x uint4 vector loads
    unsigned s = 0;
    {
        const uint4* hp = (const uint4*)(hist + (base - 63));
#pragma unroll
        for (int k = 0; k < 16; k++) {
            uint4 v = hp[k];
            s += v.x + v.y + v.z + v.w;
        }
    }
    ssum[t] = s;
    __syncthreads();
    for (int off = 1; off < 1024; off <<= 1) {
        unsigned v = (t >= off) ? ssum[t - off] : 0u;
        __syncthreads();
        ssum[t] += v;
        __syncthreads();
    }
    unsigned incl = ssum[t], excl = incl - s;
    if (excl < target && target <= incl) {
        unsigned run = excl;
        for (int k = 0; k < 64; k++) {
            unsigned c = hist[base - k];
            if (run + c >= target) { scal[2 * mode] = (unsigned)(base - k); scal[2 * mode + 1] = run; break; }
            run += c;
        }
    }
}

// ---- gather all keys >= threshold (ties after strict-greater block) ----
__global__ __launch_bounds__(256) void k_gather(const float* __restrict__ conf,
                                                unsigned* scal, unsigned long long* sel) {
    int n = blockIdx.x * 256 + threadIdx.x;
    if (n >= NANCH) return;
    unsigned B1 = scal[0], cnt1 = scal[1], B2 = scal[2], cnt2 = scal[3];
    unsigned T = (B1 << 16) | B2;
    unsigned key = fkey(conf[n]);
    if (key < T) return;
    unsigned long long kk = ((unsigned long long)(~key) << 32) | (unsigned)n;  // smaller = better rank
    if (key > T) {
        unsigned pos = atomicAdd(&scal[4], 1u);
        if (pos < 8192u) sel[pos] = kk;
    } else {
        unsigned pos = cnt1 + cnt2 + atomicAdd(&scal[5], 1u);
        if (pos < 8192u) sel[pos] = kk;
    }
}

// ---- exact rank by pairwise comparison ----
// All keys distinct (index embedded). rank = #{j : sel[j] < sel[i]}.
// Scatter topidx[rank] = idx for rank < 6000. 32 blocks x 256 threads.
__global__ __launch_bounds__(256) void k_rank(const unsigned* __restrict__ scal,
                                              const unsigned long long* __restrict__ sel,
                                              unsigned* __restrict__ topidx) {
    __shared__ unsigned long long tile[2048];
    unsigned G = scal[1] + scal[3];
    unsigned filled = G + scal[5];
    if (filled > 8192u) filled = 8192u;
    int i = blockIdx.x * 256 + threadIdx.x;
    unsigned long long mykey = (i < (int)filled) ? sel[i] : 0xFFFFFFFFFFFFFFFFull;
    int rank = 0;
    for (int t0 = 0; t0 < 8192; t0 += 2048) {
        __syncthreads();
        for (int l = threadIdx.x; l < 2048; l += 256) {
            int j = t0 + l;
            tile[l] = (j < (int)filled) ? sel[j] : 0xFFFFFFFFFFFFFFFFull;
        }
        __syncthreads();
        for (int l = 0; l < 2048; l += 4) {   // broadcast LDS reads, 4-wide
            ulonglong2 p = *(const ulonglong2*)&tile[l];
            ulonglong2 q = *(const ulonglong2*)&tile[l + 2];
            rank += (p.x < mykey) + (p.y < mykey) + (q.x < mykey) + (q.y < mykey);
        }
    }
    if (i < (int)filled && rank < PRE_N)
        topidx[rank] = (unsigned)(mykey & 0xFFFFFFFFull);
}

// ---- per-proposal: reg conv (4 channels), anchor, decode, clip, valid ----
__global__ __launch_bounds__(64) void k_prop(const float* __restrict__ x,
                                             const float* __restrict__ wreg,
                                             const float* __restrict__ breg,
                                             const unsigned* __restrict__ topidx,
                                             const int* __restrict__ imh, const int* __restrict__ imw,
                                             float* __restrict__ boxes, int* __restrict__ valid) {
    int r = blockIdx.x;
    int lane = threadIdx.x;
    unsigned n = topidx[r];
    int a = (int)(n % 9u); int p = (int)(n / 9u);
    const float* wr = wreg + (4 * a) * 256;
    float s0 = 0, s1 = 0, s2 = 0, s3 = 0;
    for (int c = lane; c < 256; c += 64) {
        float xv = x[c * HW + p];
        s0 = fmaf(wr[c], xv, s0);
        s1 = fmaf(wr[256 + c], xv, s1);
        s2 = fmaf(wr[512 + c], xv, s2);
        s3 = fmaf(wr[768 + c], xv, s3);
    }
#pragma unroll
    for (int off = 32; off >= 1; off >>= 1) {
        s0 += __shfl_down(s0, off);
        s1 += __shfl_down(s1, off);
        s2 += __shfl_down(s2, off);
        s3 += __shfl_down(s3, off);
    }
    if (lane == 0) {
        float dx = s0 + breg[4 * a], dy = s1 + breg[4 * a + 1];
        float dw = s2 + breg[4 * a + 2], dh = s3 + breg[4 * a + 3];
        int wi = p % W_, hi = p / W_;
        const double SC[3] = {32.0, 64.0, 128.0};
        const double RT[3] = {0.5, 1.0, 2.0};
        double sd = SC[a / 3], rd = RT[a % 3];
        double wb = sd * sqrt(1.0 / rd), hb = sd * sqrt(rd);
        float bx1 = (float)(-wb * 0.5), by1 = (float)(-hb * 0.5);
        float bx2 = (float)(wb * 0.5),  by2 = (float)(hb * 0.5);
        float cxs = ((float)wi + 0.5f) * 4.0f, cys = ((float)hi + 0.5f) * 4.0f;
        float x1a = cxs + bx1, y1a = cys + by1, x2a = cxs + bx2, y2a = cys + by2;
        float wa = x2a - x1a, ha = y2a - y1a;
        float cxa = x1a + 0.5f * wa, cya = y1a + 0.5f * ha;
        float cx = dx * wa + cxa, cy = dy * ha + cya;
        float ww = expf(dw) * wa, hh = expf(dh) * ha;
        float X1 = cx - 0.5f * ww, Y1 = cy - 0.5f * hh;
        float X2 = cx + 0.5f * ww, Y2 = cy + 0.5f * hh;
        float Wf = (float)(*imw), Hf = (float)(*imh);
        X1 = fminf(fmaxf(X1, 0.f), Wf); Y1 = fminf(fmaxf(Y1, 0.f), Hf);
        X2 = fminf(fmaxf(X2, 0.f), Wf); Y2 = fminf(fmaxf(Y2, 0.f), Hf);
        boxes[4 * r] = X1; boxes[4 * r + 1] = Y1; boxes[4 * r + 2] = X2; boxes[4 * r + 3] = Y2;
        valid[r] = ((X2 - X1) >= 1.0f && (Y2 - Y1) >= 1.0f) ? 1 : 0;
    }
}

// ---- NMS IoU bitmask: mask[i][jw] bit b = (j=jw*64+b > i) && iou>0.7 ----
__global__ __launch_bounds__(256) void k_mask(const float* __restrict__ boxes,
                                              unsigned long long* __restrict__ mask) {
    __shared__ float jb[256];
    int jw = blockIdx.x;
    int i = blockIdx.y * 256 + threadIdx.x;
    {
        int idx = jw * 256 + threadIdx.x;
        jb[threadIdx.x] = (idx < PRE_N * 4) ? boxes[idx] : 0.f;
    }
    __syncthreads();
    if (i >= PRE_N) return;
    float ax1 = boxes[4 * i], ay1 = boxes[4 * i + 1], ax2 = boxes[4 * i + 2], ay2 = boxes[4 * i + 3];
    float aarea = (ax2 - ax1) * (ay2 - ay1);
    unsigned long long m = 0;
    int jbase = jw * 64;
    for (int b = 0; b < 64; b++) {
        int j = jbase + b;
        if (j <= i || j >= PRE_N) continue;
        float bx1 = jb[4 * b], by1 = jb[4 * b + 1], bx2 = jb[4 * b + 2], by2 = jb[4 * b + 3];
        float barea = (bx2 - bx1) * (by2 - by1);
        float xx1 = fmaxf(ax1, bx1), yy1 = fmaxf(ay1, by1);
        float xx2 = fminf(ax2, bx2), yy2 = fminf(ay2, by2);
        float w = fmaxf(xx2 - xx1, 0.f), h = fmaxf(yy2 - yy1, 0.f);
        float inter = w * h;
        float iou = inter / (aarea + barea - inter + 1e-9f);
        if (iou > 0.7f) m |= (1ull << b);
    }
    mask[(size_t)i * NWORDS + jw] = m;
}

// ---- greedy scan: diagonal masks preloaded to LDS; serial part iterates kept bits ----
__global__ __launch_bounds__(128) void k_scan_nms(const unsigned long long* __restrict__ mask,
                                                  const int* __restrict__ valid,
                                                  const float* __restrict__ boxes,
                                                  float* __restrict__ out) {
    __shared__ unsigned long long diag[NWORDS][64];   // 48,128 B
    __shared__ unsigned long long removed[NWORDS];
    __shared__ unsigned long long validw[NWORDS];
    __shared__ int keepList[POST_N];
    __shared__ int cnt;
    __shared__ unsigned long long keptbits;
    int t = threadIdx.x;
    if (t < NWORDS) { removed[t] = 0ull; validw[t] = 0ull; }
    if (t == 0) cnt = 0;
    __syncthreads();
    for (int l = t; l < NWORDS * 64; l += 128) {
        int w = l >> 6, b = l & 63;
        int i = w * 64 + b;
        diag[w][b] = (i < PRE_N) ? mask[(size_t)i * NWORDS + w] : 0ull;
    }
    for (int i = t; i < PRE_N; i += 128)
        if (valid[i]) atomicOr(&validw[i >> 6], 1ull << (i & 63));
    __syncthreads();
    for (int w = 0; w < NWORDS; w++) {
        unsigned long long candw = validw[w] & ~removed[w];  // uniform (LDS, post-sync)
        if (!candw) continue;
        if (t == 0) {
            unsigned long long cand = candw;
            unsigned long long kb = 0ull;
            int c = cnt;
            while (cand && c < POST_N) {
                int b = __ffsll((unsigned long long)cand) - 1;
                keepList[c++] = w * 64 + b;
                kb |= 1ull << b;
                cand &= ~(1ull << b);
                cand &= ~diag[w][b];
            }
            cnt = c; keptbits = kb;
        }
        __syncthreads();
        if (cnt >= POST_N) break;
        unsigned long long kb = keptbits;
        if (kb) {
            for (int w2 = w + 1 + t; w2 < NWORDS; w2 += 128) {
                unsigned long long acc2 = removed[w2];
                unsigned long long tt = kb;
                while (tt) {
                    int b = __ffsll((unsigned long long)tt) - 1;
                    tt &= tt - 1;
                    acc2 |= mask[(size_t)(w * 64 + b) * NWORDS + w2];
                }
                removed[w2] = acc2;
            }
        }
        __syncthreads();
    }
    __syncthreads();
    int c = cnt;
    for (int e = t; e < POST_N * 4; e += 128) {
        int r = e >> 2;
        out[e] = (r < c) ? boxes[4 * keepList[r] + (e & 3)] : 0.f;
    }
}

extern "C" void kernel_launch(void* const* d_in, const int* in_sizes, int n_in,
                              void* d_out, int out_size, void* d_ws, size_t ws_size,
                              hipStream_t stream) {
    const float* feature = (const float*)d_in[0];
    const float* w1   = (const float*)d_in[1];
    const float* b1   = (const float*)d_in[2];
    const float* wcls = (const float*)d_in[3];
    const float* bcls = (const float*)d_in[4];
    const float* wreg = (const float*)d_in[5];
    const float* breg = (const float*)d_in[6];
    const int* imh = (const int*)d_in[7];
    const int* imw = (const int*)d_in[8];

    char* ws = (char*)d_ws;
    float* xbuf  = (float*)(ws + X_OFF);
    float* conf  = (float*)(ws + CONF_OFF);
    unsigned* hist1 = (unsigned*)(ws + HIST1_OFF);
    unsigned* hist2 = (unsigned*)(ws + HIST2_OFF);
    unsigned* scal  = (unsigned*)(ws + SCAL_OFF);
    unsigned long long* sel = (unsigned long long*)(ws + SEL_OFF);
    unsigned* topidx = (unsigned*)(ws + TOPIDX_OFF);
    float* boxes = (float*)(ws + BOXES_OFF);
    int* valid   = (int*)(ws + VALID_OFF);
    unsigned long long* mask = (unsigned long long*)(ws + MASK_OFF);
    float* w1r = (float*)(ws + W1R_OFF);
    float* wcr = (float*)(ws + WCR_OFF);
    float* outF = (float*)d_out;

    hipLaunchKernelGGL(k_init,   dim3(2826), dim3(256), 0, stream, w1, wcls, hist1, w1r, wcr);
    hipLaunchKernelGGL(k_conv1,  dim3(9, 25, 8), dim3(256), 0, stream, feature, w1r, b1, xbuf);
    hipLaunchKernelGGL(k_cls,    dim3(213),  dim3(256), 0, stream, xbuf, wcr, bcls, conf, hist1);
    hipLaunchKernelGGL(k_scan,   dim3(1),    dim3(1024), 0, stream, hist1, scal, 0);
    hipLaunchKernelGGL(k_hist2,  dim3(1913), dim3(256), 0, stream, conf, scal, hist2);
    hipLaunchKernelGGL(k_scan,   dim3(1),    dim3(1024), 0, stream, hist2, scal, 1);
    hipLaunchKernelGGL(k_gather, dim3(1913), dim3(256), 0, stream, conf, scal, sel);
    hipLaunchKernelGGL(k_rank,   dim3(32),   dim3(256), 0, stream, scal, sel, topidx);
    hipLaunchKernelGGL(k_prop,   dim3(PRE_N), dim3(64), 0, stream, xbuf, wreg, breg, topidx, imh, imw, boxes, valid);
    hipLaunchKernelGGL(k_mask,   dim3(NWORDS, 24), dim3(256), 0, stream, boxes, mask);
    hipLaunchKernelGGL(k_scan_nms, dim3(1), dim3(128), 0, stream, mask, valid, boxes, outF);
}

// Round 8
// 1826.113 us; speedup vs baseline: 1.4698x; 1.4698x over previous
//
#include <hip/hip_runtime.h>
#include <hip/hip_bf16.h>
#include <hip/hip_cooperative_groups.h>
#include <math.h>

namespace cg = cooperative_groups;

#define H_ 200
#define W_ 272
#define C_ 256
#define HW 54400
#define NANCH 489600
#define PRE_N 6000
#define POST_N 1000
#define NWORDS 94    // ceil(6000/64)
#define CHUNK_W 2720 // 8 ic * 10 rows * 34 cols halo

// ---- workspace layout (bytes) ----
#define X_OFF       0ull                 // 256*54400*4 = 55,705,600
#define CONF_OFF    55705600ull          // 489600*4   =  1,958,400
#define HIST1_OFF   57664000ull          // 65536*4    =    262,144
#define HIST2_OFF   57926144ull          // 65536*4    =    262,144
#define SCAL_OFF    58188288ull          // 64*4
#define SEL_OFF     58188544ull          // 8192*8     =     65,536
#define TOPIDX_OFF  58254080ull          // 6000*4
#define BOXES_OFF   58278080ull          // 6000*4*4
#define VALID_OFF   58374080ull          // 6000*4
#define MASK_OFF    58398080ull          // 6000*94*8  =  4,512,000
#define W1R_OFF     62910080ull          // [32][256][9][8]*4 = 2,359,296
#define WCR_OFF     65269376ull          // 9*256*4

__device__ __forceinline__ unsigned fkey(float fv) {
    unsigned u = __float_as_uint(fv);
    return (u & 0x80000000u) ? ~u : (u | 0x80000000u);  // monotone: bigger float -> bigger key
}

// ---- clear histograms + repack weights, one launch ----
__global__ __launch_bounds__(256) void k_init(const float* __restrict__ w1,
                                              const float* __restrict__ wcls,
                                              unsigned* __restrict__ hist1,
                                              float* __restrict__ w1r,
                                              float* __restrict__ wcr) {
    int e = blockIdx.x * 256 + threadIdx.x;
    if (e < 131136) hist1[e] = 0u;
    int e1 = e - 131136;
    if (e1 >= 0 && e1 < 589824) {
        int oc = e1 / 2304; int rem = e1 % 2304; int ic = rem / 9; int k = rem % 9;
        int wg = oc >> 3, o = oc & 7;
        w1r[(((size_t)wg * 256 + ic) * 9 + k) * 8 + o] = w1[e1];
    } else if (e1 >= 589824 && e1 < 589824 + 2304) {
        int e2 = e1 - 589824; int a = e2 / 256; int c = e2 % 256;
        wcr[c * 9 + a] = wcls[e2];
    }
}

// ---- 3x3 conv + bias + relu. R6 winner verbatim: SGPR weights, 8-ic double
// buffer, one barrier/chunk, explicit b128/b64 LDS reads. ----
__global__ __launch_bounds__(256) void k_conv1(const float* __restrict__ f,
                                               const float* __restrict__ w1r,
                                               const float* __restrict__ b1,
                                               float* __restrict__ xo) {
    __shared__ __align__(16) float sI[2][2880];   // 2 x 11,520 B
    int tid = threadIdx.x;
    int lane = tid & 63;
    int wgl = __builtin_amdgcn_readfirstlane(tid >> 6);
    int xg = lane & 7;
    int yg = lane >> 3;
    int X0 = blockIdx.x * 32;
    int Y0 = blockIdx.y * 8;
    int wg = blockIdx.z * 4 + wgl;
    int y = Y0 + yg;
    int xbase = X0 + xg * 4;

    int off[11]; int lds[11]; bool ok[11];
#pragma unroll
    for (int it = 0; it < 11; it++) {
        int l = tid + it * 256;
        int ci = l / 340; int r = l - ci * 340; int ry = r / 34; int rx = r - ry * 34;
        int gx = X0 - 1 + rx, gy = Y0 - 1 + ry;
        ok[it] = (l < CHUNK_W) && gx >= 0 && gx < W_ && gy >= 0 && gy < H_;
        off[it] = ci * HW + gy * W_ + gx;
        lds[it] = (ci * 10 + ry) * 36 + rx;
    }
    float rbuf[11];
#pragma unroll
    for (int it = 0; it < 11; it++)
        rbuf[it] = ok[it] ? f[off[it]] : 0.f;
#pragma unroll
    for (int it = 0; it < 11; it++)
        if (tid + it * 256 < CHUNK_W) sI[0][lds[it]] = rbuf[it];
    __syncthreads();

    float acc[8][4];
#pragma unroll
    for (int o = 0; o < 8; o++)
#pragma unroll
        for (int i = 0; i < 4; i++) acc[o][i] = 0.f;

    const float* wbase = w1r + (size_t)wg * 256 * 72;

    int cur = 0;
    for (int ic0 = 0; ic0 < 256; ic0 += 8) {
        if (ic0 < 248) {
            const float* fn = f + (size_t)(ic0 + 8) * HW;
#pragma unroll
            for (int it = 0; it < 11; it++)
                rbuf[it] = ok[it] ? fn[off[it]] : 0.f;
        }
        const float* sbuf = sI[cur];
        for (int ci = 0; ci < 8; ci++) {
            const float* wp = wbase + (size_t)(ic0 + ci) * 72;
#pragma unroll
            for (int ky = 0; ky < 3; ky++) {
                const float* irow = &sbuf[(ci * 10 + yg + ky) * 36 + xg * 4];
                float4 va = *(const float4*)irow;
                float2 vb = *(const float2*)(irow + 4);
                float in[6] = {va.x, va.y, va.z, va.w, vb.x, vb.y};
                const float* wrow = wp + ky * 24;
#pragma unroll
                for (int kx = 0; kx < 3; kx++) {
#pragma unroll
                    for (int o = 0; o < 8; o++) {
                        float w = wrow[kx * 8 + o];
#pragma unroll
                        for (int i = 0; i < 4; i++)
                            acc[o][i] = fmaf(w, in[i + kx], acc[o][i]);
                    }
                }
            }
        }
        if (ic0 < 248) {
#pragma unroll
            for (int it = 0; it < 11; it++)
                if (tid + it * 256 < CHUNK_W) sI[cur ^ 1][lds[it]] = rbuf[it];
        }
        __syncthreads();
        cur ^= 1;
    }
#pragma unroll
    for (int o = 0; o < 8; o++) {
        int oc = wg * 8 + o;
        float bv = b1[oc];
        float* orow = xo + (size_t)oc * HW + y * W_ + xbase;
        float v0 = fmaxf(acc[o][0] + bv, 0.f), v1 = fmaxf(acc[o][1] + bv, 0.f);
        float v2 = fmaxf(acc[o][2] + bv, 0.f), v3 = fmaxf(acc[o][3] + bv, 0.f);
        if (xbase + 3 < W_) {
            *(float4*)orow = make_float4(v0, v1, v2, v3);
        } else {
            float vv[4] = {v0, v1, v2, v3};
            for (int i = 0; i < 4; i++)
                if (xbase + i < W_) orow[i] = vv[i];
        }
    }
}

// ---- fused post-conv pipeline: one cooperative kernel, 256 blocks x 256 thr.
// Phases (grid.sync between): cls+hist1 | scan0 | hist2 | scan1 | gather |
// rank | prop | mask | scan_nms. Saves ~9 dependent dispatches (each costs an
// agent-scope acquire/release + dispatch latency). Phase bodies verbatim from
// R6/R7 kernels -> bitwise-identical output.
union SharedU {
    unsigned ssum[256];
    unsigned long long tile[2048];                 // 16 KB (rank)
    float jb[256];                                 // mask
    struct {
        unsigned long long diag[NWORDS][64];       // 48 KB
        unsigned long long removed[NWORDS];
        unsigned long long validw[NWORDS];
        int keepList[POST_N];
        int cnt;
        unsigned long long keptbits;
    } nms;                                         // ~53.6 KB
};

__global__ __launch_bounds__(256) void k_post(const float* __restrict__ x,
                                              const float* __restrict__ wcr,
                                              const float* __restrict__ bc,
                                              float* __restrict__ conf,
                                              unsigned* __restrict__ hist1,
                                              unsigned* __restrict__ hist2,
                                              unsigned* __restrict__ scal,
                                              unsigned long long* __restrict__ sel,
                                              unsigned* __restrict__ topidx,
                                              const float* __restrict__ wreg,
                                              const float* __restrict__ breg,
                                              const int* __restrict__ imh,
                                              const int* __restrict__ imw,
                                              float* __restrict__ boxes,
                                              int* __restrict__ validA,
                                              unsigned long long* __restrict__ mask,
                                              float* __restrict__ out) {
    __shared__ SharedU su;
    cg::grid_group grid = cg::this_grid();
    int t = threadIdx.x;
    int gid = blockIdx.x * 256 + t;

    // ---- Phase A: 1x1 cls conv + histogram pass 1 ----
    for (int p = gid; p < HW; p += 65536) {
        float acc[9];
#pragma unroll
        for (int a = 0; a < 9; a++) acc[a] = 0.f;
        for (int c = 0; c < 256; c++) {
            float xv = x[c * HW + p];
            const float* wp = wcr + c * 9;
#pragma unroll
            for (int a = 0; a < 9; a++) acc[a] = fmaf(wp[a], xv, acc[a]);
        }
#pragma unroll
        for (int a = 0; a < 9; a++) {
            float v = acc[a] + bc[a];
            conf[p * 9 + a] = v;
            atomicAdd(&hist1[fkey(v) >> 16], 1u);
        }
    }
    grid.sync();

    // ---- Phase B0: descending scan of hist1 (block 0) ----
    if (blockIdx.x == 0) {
        unsigned target = 6000u;
        int base = 65535 - t * 256;
        unsigned s = 0;
        const uint4* hp = (const uint4*)(hist1 + (base - 255));
        for (int k = 0; k < 64; k++) { uint4 v = hp[k]; s += v.x + v.y + v.z + v.w; }
        su.ssum[t] = s;
        __syncthreads();
        for (int o = 1; o < 256; o <<= 1) {
            unsigned v = (t >= o) ? su.ssum[t - o] : 0u;
            __syncthreads();
            su.ssum[t] += v;
            __syncthreads();
        }
        unsigned incl = su.ssum[t], excl = incl - s;
        if (excl < target && target <= incl) {
            unsigned run = excl;
            for (int k = 0; k < 256; k++) {
                unsigned c = hist1[base - k];
                if (run + c >= target) { scal[0] = (unsigned)(base - k); scal[1] = run; break; }
                run += c;
            }
        }
    }
    grid.sync();

    // ---- Phase C: histogram pass 2 ----
    {
        unsigned B1 = scal[0];
        for (int n = gid; n < NANCH; n += 65536) {
            unsigned key = fkey(conf[n]);
            if ((key >> 16) == B1) atomicAdd(&hist2[key & 0xFFFFu], 1u);
        }
    }
    grid.sync();

    // ---- Phase B1: descending scan of hist2 (block 0) ----
    if (blockIdx.x == 0) {
        unsigned target = 6000u - scal[1];
        int base = 65535 - t * 256;
        unsigned s = 0;
        const uint4* hp = (const uint4*)(hist2 + (base - 255));
        for (int k = 0; k < 64; k++) { uint4 v = hp[k]; s += v.x + v.y + v.z + v.w; }
        su.ssum[t] = s;
        __syncthreads();
        for (int o = 1; o < 256; o <<= 1) {
            unsigned v = (t >= o) ? su.ssum[t - o] : 0u;
            __syncthreads();
            su.ssum[t] += v;
            __syncthreads();
        }
        unsigned incl = su.ssum[t], excl = incl - s;
        if (excl < target && target <= incl) {
            unsigned run = excl;
            for (int k = 0; k < 256; k++) {
                unsigned c = hist2[base - k];
                if (run + c >= target) { scal[2] = (unsigned)(base - k); scal[3] = run; break; }
                run += c;
            }
        }
    }
    grid.sync();

    // ---- Phase E: gather keys >= threshold ----
    {
        unsigned B1 = scal[0], cnt1 = scal[1], B2 = scal[2], cnt2 = scal[3];
        unsigned T = (B1 << 16) | B2;
        for (int n = gid; n < NANCH; n += 65536) {
            unsigned key = fkey(conf[n]);
            if (key < T) continue;
            unsigned long long kk = ((unsigned long long)(~key) << 32) | (unsigned)n;
            if (key > T) {
                unsigned pos = atomicAdd(&scal[4], 1u);
                if (pos < 8192u) sel[pos] = kk;
            } else {
                unsigned pos = cnt1 + cnt2 + atomicAdd(&scal[5], 1u);
                if (pos < 8192u) sel[pos] = kk;
            }
        }
    }
    grid.sync();

    // ---- Phase F: exact rank by pairwise comparison (blocks 0..31) ----
    {
        unsigned G = scal[1] + scal[3];
        unsigned filled = G + scal[5];
        if (filled > 8192u) filled = 8192u;
        if (blockIdx.x < 32) {
            int i = blockIdx.x * 256 + t;
            unsigned long long mykey = (i < (int)filled) ? sel[i] : 0xFFFFFFFFFFFFFFFFull;
            int rank = 0;
            for (int t0 = 0; t0 < 8192; t0 += 2048) {
                __syncthreads();
                for (int l = t; l < 2048; l += 256) {
                    int j = t0 + l;
                    su.tile[l] = (j < (int)filled) ? sel[j] : 0xFFFFFFFFFFFFFFFFull;
                }
                __syncthreads();
                for (int l = 0; l < 2048; l += 4) {
                    ulonglong2 p = *(const ulonglong2*)&su.tile[l];
                    ulonglong2 q = *(const ulonglong2*)&su.tile[l + 2];
                    rank += (p.x < mykey) + (p.y < mykey) + (q.x < mykey) + (q.y < mykey);
                }
            }
            if (i < (int)filled && rank < PRE_N)
                topidx[rank] = (unsigned)(mykey & 0xFFFFFFFFull);
        }
    }
    grid.sync();

    // ---- Phase G: per-proposal reg conv + decode + clip (grid-stride by wave) ----
    {
        int wave = blockIdx.x * 4 + (t >> 6);
        int lane = t & 63;
        for (int r = wave; r < PRE_N; r += 1024) {
            unsigned n = topidx[r];
            int a = (int)(n % 9u); int p = (int)(n / 9u);
            const float* wr = wreg + (4 * a) * 256;
            float s0 = 0, s1 = 0, s2 = 0, s3 = 0;
            for (int c = lane; c < 256; c += 64) {
                float xv = x[c * HW + p];
                s0 = fmaf(wr[c], xv, s0);
                s1 = fmaf(wr[256 + c], xv, s1);
                s2 = fmaf(wr[512 + c], xv, s2);
                s3 = fmaf(wr[768 + c], xv, s3);
            }
#pragma unroll
            for (int o = 32; o >= 1; o >>= 1) {
                s0 += __shfl_down(s0, o);
                s1 += __shfl_down(s1, o);
                s2 += __shfl_down(s2, o);
                s3 += __shfl_down(s3, o);
            }
            if (lane == 0) {
                float dx = s0 + breg[4 * a], dy = s1 + breg[4 * a + 1];
                float dw = s2 + breg[4 * a + 2], dh = s3 + breg[4 * a + 3];
                int wi = p % W_, hi = p / W_;
                const double SC[3] = {32.0, 64.0, 128.0};
                const double RT[3] = {0.5, 1.0, 2.0};
                double sd = SC[a / 3], rd = RT[a % 3];
                double wb = sd * sqrt(1.0 / rd), hb = sd * sqrt(rd);
                float bx1 = (float)(-wb * 0.5), by1 = (float)(-hb * 0.5);
                float bx2 = (float)(wb * 0.5),  by2 = (float)(hb * 0.5);
                float cxs = ((float)wi + 0.5f) * 4.0f, cys = ((float)hi + 0.5f) * 4.0f;
                float x1a = cxs + bx1, y1a = cys + by1, x2a = cxs + bx2, y2a = cys + by2;
                float wa = x2a - x1a, ha = y2a - y1a;
                float cxa = x1a + 0.5f * wa, cya = y1a + 0.5f * ha;
                float cx = dx * wa + cxa, cy = dy * ha + cya;
                float ww = expf(dw) * wa, hh = expf(dh) * ha;
                float X1 = cx - 0.5f * ww, Y1 = cy - 0.5f * hh;
                float X2 = cx + 0.5f * ww, Y2 = cy + 0.5f * hh;
                float Wf = (float)(*imw), Hf = (float)(*imh);
                X1 = fminf(fmaxf(X1, 0.f), Wf); Y1 = fminf(fmaxf(Y1, 0.f), Hf);
                X2 = fminf(fmaxf(X2, 0.f), Wf); Y2 = fminf(fmaxf(Y2, 0.f), Hf);
                boxes[4 * r] = X1; boxes[4 * r + 1] = Y1; boxes[4 * r + 2] = X2; boxes[4 * r + 3] = Y2;
                validA[r] = ((X2 - X1) >= 1.0f && (Y2 - Y1) >= 1.0f) ? 1 : 0;
            }
        }
    }
    grid.sync();

    // ---- Phase H: NMS IoU bitmask (tile grid-stride, jb staged per tile) ----
    for (int tile = blockIdx.x; tile < NWORDS * 24; tile += 256) {
        int jw = tile / 24, ib = tile - jw * 24;
        __syncthreads();
        {
            int idx = jw * 256 + t;
            su.jb[t] = (idx < PRE_N * 4) ? boxes[idx] : 0.f;
        }
        __syncthreads();
        int i = ib * 256 + t;
        if (i < PRE_N) {
            float ax1 = boxes[4 * i], ay1 = boxes[4 * i + 1], ax2 = boxes[4 * i + 2], ay2 = boxes[4 * i + 3];
            float aarea = (ax2 - ax1) * (ay2 - ay1);
            unsigned long long m = 0;
            int jbase = jw * 64;
            for (int b = 0; b < 64; b++) {
                int j = jbase + b;
                if (j <= i || j >= PRE_N) continue;
                float bx1 = su.jb[4 * b], by1 = su.jb[4 * b + 1], bx2 = su.jb[4 * b + 2], by2 = su.jb[4 * b + 3];
                float barea = (bx2 - bx1) * (by2 - by1);
                float xx1 = fmaxf(ax1, bx1), yy1 = fmaxf(ay1, by1);
                float xx2 = fminf(ax2, bx2), yy2 = fminf(ay2, by2);
                float w = fmaxf(xx2 - xx1, 0.f), h = fmaxf(yy2 - yy1, 0.f);
                float inter = w * h;
                float iou = inter / (aarea + barea - inter + 1e-9f);
                if (iou > 0.7f) m |= (1ull << b);
            }
            mask[(size_t)i * NWORDS + jw] = m;
        }
    }
    grid.sync();

    // ---- Phase I: greedy NMS scan + compaction (block 0) ----
    if (blockIdx.x == 0) {
        if (t < NWORDS) { su.nms.removed[t] = 0ull; su.nms.validw[t] = 0ull; }
        if (t == 0) su.nms.cnt = 0;
        __syncthreads();
        for (int l = t; l < NWORDS * 64; l += 256) {
            int w = l >> 6, b = l & 63;
            int i = w * 64 + b;
            su.nms.diag[w][b] = (i < PRE_N) ? mask[(size_t)i * NWORDS + w] : 0ull;
        }
        for (int i = t; i < PRE_N; i += 256)
            if (validA[i]) atomicOr(&su.nms.validw[i >> 6], 1ull << (i & 63));
        __syncthreads();
        for (int w = 0; w < NWORDS; w++) {
            unsigned long long candw = su.nms.validw[w] & ~su.nms.removed[w];
            if (!candw) continue;
            if (t == 0) {
                unsigned long long cand = candw;
                unsigned long long kb = 0ull;
                int c = su.nms.cnt;
                while (cand && c < POST_N) {
                    int b = __ffsll((unsigned long long)cand) - 1;
                    su.nms.keepList[c++] = w * 64 + b;
                    kb |= 1ull << b;
                    cand &= ~(1ull << b);
                    cand &= ~su.nms.diag[w][b];
                }
                su.nms.cnt = c; su.nms.keptbits = kb;
            }
            __syncthreads();
            if (su.nms.cnt >= POST_N) break;
            unsigned long long kb = su.nms.keptbits;
            if (kb) {
                for (int w2 = w + 1 + t; w2 < NWORDS; w2 += 256) {
                    unsigned long long acc2 = su.nms.removed[w2];
                    unsigned long long tt = kb;
                    while (tt) {
                        int b = __ffsll((unsigned long long)tt) - 1;
                        tt &= tt - 1;
                        acc2 |= mask[(size_t)(w * 64 + b) * NWORDS + w2];
                    }
                    su.nms.removed[w2] = acc2;
                }
            }
            __syncthreads();
        }
        __syncthreads();
        int c = su.nms.cnt;
        for (int e = t; e < POST_N * 4; e += 256) {
            int r = e >> 2;
            out[e] = (r < c) ? boxes[4 * su.nms.keepList[r] + (e & 3)] : 0.f;
        }
    }
}

extern "C" void kernel_launch(void* const* d_in, const int* in_sizes, int n_in,
                              void* d_out, int out_size, void* d_ws, size_t ws_size,
                              hipStream_t stream) {
    const float* feature = (const float*)d_in[0];
    const float* w1   = (const float*)d_in[1];
    const float* b1   = (const float*)d_in[2];
    const float* wcls = (const float*)d_in[3];
    const float* bcls = (const float*)d_in[4];
    const float* wreg = (const float*)d_in[5];
    const float* breg = (const float*)d_in[6];
    const int* imh = (const int*)d_in[7];
    const int* imw = (const int*)d_in[8];

    char* ws = (char*)d_ws;
    float* xbuf  = (float*)(ws + X_OFF);
    float* conf  = (float*)(ws + CONF_OFF);
    unsigned* hist1 = (unsigned*)(ws + HIST1_OFF);
    unsigned* hist2 = (unsigned*)(ws + HIST2_OFF);
    unsigned* scal  = (unsigned*)(ws + SCAL_OFF);
    unsigned long long* sel = (unsigned long long*)(ws + SEL_OFF);
    unsigned* topidx = (unsigned*)(ws + TOPIDX_OFF);
    float* boxes = (float*)(ws + BOXES_OFF);
    int* valid   = (int*)(ws + VALID_OFF);
    unsigned long long* mask = (unsigned long long*)(ws + MASK_OFF);
    float* w1r = (float*)(ws + W1R_OFF);
    float* wcr = (float*)(ws + WCR_OFF);
    float* outF = (float*)d_out;

    hipLaunchKernelGGL(k_init,  dim3(2826), dim3(256), 0, stream, w1, wcls, hist1, w1r, wcr);
    hipLaunchKernelGGL(k_conv1, dim3(9, 25, 8), dim3(256), 0, stream, feature, w1r, b1, xbuf);

    void* args[] = {(void*)&xbuf, (void*)&wcr, (void*)&bcls, (void*)&conf,
                    (void*)&hist1, (void*)&hist2, (void*)&scal, (void*)&sel,
                    (void*)&topidx, (void*)&wreg, (void*)&breg, (void*)&imh,
                    (void*)&imw, (void*)&boxes, (void*)&valid, (void*)&mask,
                    (void*)&outF};
    hipLaunchCooperativeKernel((void*)k_post, dim3(256), dim3(256), args, 0, stream);
}

// Round 9
// 1553.508 us; speedup vs baseline: 1.7277x; 1.1755x over previous
//
#include <hip/hip_runtime.h>
#include <hip/hip_bf16.h>
#include <math.h>

#define H_ 200
#define W_ 272
#define C_ 256
#define HW 54400
#define NANCH 489600
#define PRE_N 6000
#define POST_N 1000
#define NWORDS 94    // ceil(6000/64)
#define CHUNK_W 2720 // 8 ic * 10 rows * 34 cols halo
#define SELCAP 16384

// ---- workspace layout (bytes) ----
#define X_OFF       0ull                 // 256*54400*4 = 55,705,600
#define CONF_OFF    55705600ull          // 489600*4   =  1,958,400
#define HIST1_OFF   57664000ull          // 65536*4    =    262,144
#define SEL_OFF     57926144ull          // 16384*8    =    131,072  (old hist2 slot)
#define SCAL_OFF    58188288ull          // 64*4
#define TOPIDX_OFF  58254080ull          // 6000*4
#define BOXES_OFF   58278080ull          // 6000*4*4
#define VALID_OFF   58374080ull          // 6000*4
#define MASK_OFF    58398080ull          // 6000*94*8  =  4,512,000
#define WCR_OFF     65269376ull          // 9*256*4

__device__ __forceinline__ unsigned fkey(float fv) {
    unsigned u = __float_as_uint(fv);
    return (u & 0x80000000u) ? ~u : (u | 0x80000000u);  // monotone: bigger float -> bigger key
}

// ---- 3x3 conv + bias + relu. R6 winner structure: SGPR weights (now raw w1),
// 8-ic double buffer, one barrier/chunk, explicit b128/b64 LDS reads.
// Also: clears hist1/scal/sel and repacks wcr (block 0) at kernel head,
// eliminating the former k_init launch. FMA order unchanged (bitwise-stable).
__global__ __launch_bounds__(256) void k_conv1(const float* __restrict__ f,
                                               const float* __restrict__ w1,
                                               const float* __restrict__ b1,
                                               float* __restrict__ xo,
                                               unsigned* __restrict__ hist1,
                                               unsigned* __restrict__ scal,
                                               unsigned long long* __restrict__ sel,
                                               const float* __restrict__ wcls,
                                               float* __restrict__ wcr) {
    __shared__ __align__(16) float sI[2][2880];   // 2 x 11,520 B
    int tid = threadIdx.x;
    int fb = blockIdx.x + 9 * (blockIdx.y + 25 * blockIdx.z);
    // workspace init (replaces k_init): 65536 hist + 64 scal + 32768 sel-words
    {
        int g = fb * 256 + tid;
        if (g < 65536) hist1[g] = 0u;
        else if (g < 65600) scal[g - 65536] = 0u;
        else if (g < 98368) ((unsigned*)sel)[g - 65600] = 0xFFFFFFFFu;
    }
    if (fb == 0) {
        for (int e = tid; e < 2304; e += 256) {
            int a = e / 256, c = e % 256;
            wcr[c * 9 + a] = wcls[e];
        }
    }
    int lane = tid & 63;
    int wgl = __builtin_amdgcn_readfirstlane(tid >> 6);
    int xg = lane & 7;
    int yg = lane >> 3;
    int X0 = blockIdx.x * 32;
    int Y0 = blockIdx.y * 8;
    int wg = blockIdx.z * 4 + wgl;   // oc-group of 8, wave-uniform
    int y = Y0 + yg;
    int xbase = X0 + xg * 4;

    int off[11]; int lds[11]; bool ok[11];
#pragma unroll
    for (int it = 0; it < 11; it++) {
        int l = tid + it * 256;
        int ci = l / 340; int r = l - ci * 340; int ry = r / 34; int rx = r - ry * 34;
        int gx = X0 - 1 + rx, gy = Y0 - 1 + ry;
        ok[it] = (l < CHUNK_W) && gx >= 0 && gx < W_ && gy >= 0 && gy < H_;
        off[it] = ci * HW + gy * W_ + gx;
        lds[it] = (ci * 10 + ry) * 36 + rx;
    }
    float rbuf[11];
#pragma unroll
    for (int it = 0; it < 11; it++)
        rbuf[it] = ok[it] ? f[off[it]] : 0.f;
#pragma unroll
    for (int it = 0; it < 11; it++)
        if (tid + it * 256 < CHUNK_W) sI[0][lds[it]] = rbuf[it];
    __syncthreads();

    float acc[8][4];
#pragma unroll
    for (int o = 0; o < 8; o++)
#pragma unroll
        for (int i = 0; i < 4; i++) acc[o][i] = 0.f;

    const float* wbase = w1 + (size_t)(wg * 8) * 2304;  // raw OIHW, wave-uniform

    int cur = 0;
    for (int ic0 = 0; ic0 < 256; ic0 += 8) {
        if (ic0 < 248) {
            const float* fn = f + (size_t)(ic0 + 8) * HW;
#pragma unroll
            for (int it = 0; it < 11; it++)
                rbuf[it] = ok[it] ? fn[off[it]] : 0.f;
        }
        const float* sbuf = sI[cur];
        for (int ci = 0; ci < 8; ci++) {
            const float* wci = wbase + (ic0 + ci) * 9;   // + o*2304 + ky*3 + kx
#pragma unroll
            for (int ky = 0; ky < 3; ky++) {
                const float* irow = &sbuf[(ci * 10 + yg + ky) * 36 + xg * 4];
                float4 va = *(const float4*)irow;
                float2 vb = *(const float2*)(irow + 4);
                float in[6] = {va.x, va.y, va.z, va.w, vb.x, vb.y};
#pragma unroll
                for (int kx = 0; kx < 3; kx++) {
#pragma unroll
                    for (int o = 0; o < 8; o++) {
                        float w = wci[o * 2304 + ky * 3 + kx];   // s_load, uniform
#pragma unroll
                        for (int i = 0; i < 4; i++)
                            acc[o][i] = fmaf(w, in[i + kx], acc[o][i]);
                    }
                }
            }
        }
        if (ic0 < 248) {
#pragma unroll
            for (int it = 0; it < 11; it++)
                if (tid + it * 256 < CHUNK_W) sI[cur ^ 1][lds[it]] = rbuf[it];
        }
        __syncthreads();
        cur ^= 1;
    }
#pragma unroll
    for (int o = 0; o < 8; o++) {
        int oc = wg * 8 + o;
        float bv = b1[oc];
        float* orow = xo + (size_t)oc * HW + y * W_ + xbase;
        float v0 = fmaxf(acc[o][0] + bv, 0.f), v1 = fmaxf(acc[o][1] + bv, 0.f);
        float v2 = fmaxf(acc[o][2] + bv, 0.f), v3 = fmaxf(acc[o][3] + bv, 0.f);
        if (xbase + 3 < W_) {
            *(float4*)orow = make_float4(v0, v1, v2, v3);
        } else {
            float vv[4] = {v0, v1, v2, v3};
            for (int i = 0; i < 4; i++)
                if (xbase + i < W_) orow[i] = vv[i];
        }
    }
}

// ---- 1x1 cls conv -> conf[p*9+a], fused radix histogram ----
__global__ __launch_bounds__(256) void k_cls(const float* __restrict__ x,
                                             const float* __restrict__ wcr,
                                             const float* __restrict__ bc,
                                             float* __restrict__ conf,
                                             unsigned* __restrict__ hist) {
    int p = blockIdx.x * 256 + threadIdx.x;
    if (p >= HW) return;
    float acc[9];
#pragma unroll
    for (int a = 0; a < 9; a++) acc[a] = 0.f;
    for (int c = 0; c < 256; c++) {
        float xv = x[c * HW + p];
        const float* wp = wcr + c * 9;  // uniform -> s_load
#pragma unroll
        for (int a = 0; a < 9; a++) acc[a] = fmaf(wp[a], xv, acc[a]);
    }
#pragma unroll
    for (int a = 0; a < 9; a++) {
        float v = acc[a] + bc[a];
        conf[p * 9 + a] = v;
        atomicAdd(&hist[fkey(v) >> 16], 1u);
    }
}

// ---- descending scan of 65536-bin histogram: find bin of the 6000th largest.
// Owner-thread tail prefetches 32 bins/batch into registers (no dependent
// global-load chain). Writes scal[0]=B1, scal[1]=count strictly above bin. ----
__global__ __launch_bounds__(1024) void k_scan(const unsigned* __restrict__ hist,
                                               unsigned* scal) {
    __shared__ unsigned ssum[1024];
    int t = threadIdx.x;
    int base = 65535 - t * 64;
    unsigned s = 0;
    {
        const uint4* hp = (const uint4*)(hist + (base - 63));
#pragma unroll
        for (int k = 0; k < 16; k++) { uint4 v = hp[k]; s += v.x + v.y + v.z + v.w; }
    }
    ssum[t] = s;
    __syncthreads();
    for (int off = 1; off < 1024; off <<= 1) {
        unsigned v = (t >= off) ? ssum[t - off] : 0u;
        __syncthreads();
        ssum[t] += v;
        __syncthreads();
    }
    unsigned incl = ssum[t], excl = incl - s;
    if (excl < 6000u && 6000u <= incl) {
        unsigned run = excl;
        bool found = false;
        for (int pass = 0; pass < 2 && !found; pass++) {
            unsigned c32[32];
#pragma unroll
            for (int j = 0; j < 32; j++) c32[j] = hist[base - (pass * 32 + j)];
            for (int j = 0; j < 32; j++) {
                if (run + c32[j] >= 6000u) {
                    scal[0] = (unsigned)(base - (pass * 32 + j));
                    scal[1] = run;
                    found = true;
                    break;
                }
                run += c32[j];
            }
        }
    }
}

// ---- single-pass gather: every key with prefix >= B1 ----
// prefix>B1 (exactly cnt1 of them) packed at [0,cnt1); prefix==B1 after.
// sel pre-cleared to 0xFF (by conv) -> unwritten slots never out-rank real keys.
__global__ __launch_bounds__(256) void k_gather(const float* __restrict__ conf,
                                                unsigned* scal, unsigned long long* sel) {
    int n = blockIdx.x * 256 + threadIdx.x;
    if (n >= NANCH) return;
    unsigned B1 = scal[0], cnt1 = scal[1];
    unsigned key = fkey(conf[n]);
    unsigned pre = key >> 16;
    if (pre < B1) return;
    unsigned long long kk = ((unsigned long long)(~key) << 32) | (unsigned)n;  // smaller = better
    if (pre > B1) {
        unsigned pos = atomicAdd(&scal[4], 1u);      // < cnt1 <= 5999 by construction
        sel[pos] = kk;
    } else {
        unsigned pos = cnt1 + atomicAdd(&scal[5], 1u);
        if (pos < SELCAP) sel[pos] = kk;
    }
}

// ---- exact rank by pairwise comparison over [0, SELCAP) with early-out ----
__global__ __launch_bounds__(256) void k_rank(const unsigned* __restrict__ scal,
                                              const unsigned long long* __restrict__ sel,
                                              unsigned* __restrict__ topidx) {
    __shared__ unsigned long long tile[2048];
    unsigned filled = scal[1] + scal[5];
    if (filled > SELCAP) filled = SELCAP;
    int i = blockIdx.x * 256 + threadIdx.x;
    unsigned long long mykey = sel[i];
    int rank = 0;
    for (int t0 = 0; t0 < SELCAP; t0 += 2048) {
        if (t0 >= (int)filled) break;   // uniform across block
        __syncthreads();
        for (int l = threadIdx.x; l < 2048; l += 256)
            tile[l] = sel[t0 + l];
        __syncthreads();
        for (int l = 0; l < 2048; l += 4) {
            ulonglong2 p = *(const ulonglong2*)&tile[l];
            ulonglong2 q = *(const ulonglong2*)&tile[l + 2];
            rank += (p.x < mykey) + (p.y < mykey) + (q.x < mykey) + (q.y < mykey);
        }
    }
    if (i < (int)filled && rank < PRE_N)
        topidx[rank] = (unsigned)(mykey & 0xFFFFFFFFull);
}

// ---- per-proposal: reg conv (4 channels), anchor, decode, clip, valid ----
__global__ __launch_bounds__(64) void k_prop(const float* __restrict__ x,
                                             const float* __restrict__ wreg,
                                             const float* __restrict__ breg,
                                             const unsigned* __restrict__ topidx,
                                             const int* __restrict__ imh, const int* __restrict__ imw,
                                             float* __restrict__ boxes, int* __restrict__ valid) {
    int r = blockIdx.x;
    int lane = threadIdx.x;
    unsigned n = topidx[r];
    int a = (int)(n % 9u); int p = (int)(n / 9u);
    const float* wr = wreg + (4 * a) * 256;
    float s0 = 0, s1 = 0, s2 = 0, s3 = 0;
    for (int c = lane; c < 256; c += 64) {
        float xv = x[c * HW + p];
        s0 = fmaf(wr[c], xv, s0);
        s1 = fmaf(wr[256 + c], xv, s1);
        s2 = fmaf(wr[512 + c], xv, s2);
        s3 = fmaf(wr[768 + c], xv, s3);
    }
#pragma unroll
    for (int off = 32; off >= 1; off >>= 1) {
        s0 += __shfl_down(s0, off);
        s1 += __shfl_down(s1, off);
        s2 += __shfl_down(s2, off);
        s3 += __shfl_down(s3, off);
    }
    if (lane == 0) {
        float dx = s0 + breg[4 * a], dy = s1 + breg[4 * a + 1];
        float dw = s2 + breg[4 * a + 2], dh = s3 + breg[4 * a + 3];
        int wi = p % W_, hi = p / W_;
        const double SC[3] = {32.0, 64.0, 128.0};
        const double RT[3] = {0.5, 1.0, 2.0};
        double sd = SC[a / 3], rd = RT[a % 3];
        double wb = sd * sqrt(1.0 / rd), hb = sd * sqrt(rd);
        float bx1 = (float)(-wb * 0.5), by1 = (float)(-hb * 0.5);
        float bx2 = (float)(wb * 0.5),  by2 = (float)(hb * 0.5);
        float cxs = ((float)wi + 0.5f) * 4.0f, cys = ((float)hi + 0.5f) * 4.0f;
        float x1a = cxs + bx1, y1a = cys + by1, x2a = cxs + bx2, y2a = cys + by2;
        float wa = x2a - x1a, ha = y2a - y1a;
        float cxa = x1a + 0.5f * wa, cya = y1a + 0.5f * ha;
        float cx = dx * wa + cxa, cy = dy * ha + cya;
        float ww = expf(dw) * wa, hh = expf(dh) * ha;
        float X1 = cx - 0.5f * ww, Y1 = cy - 0.5f * hh;
        float X2 = cx + 0.5f * ww, Y2 = cy + 0.5f * hh;
        float Wf = (float)(*imw), Hf = (float)(*imh);
        X1 = fminf(fmaxf(X1, 0.f), Wf); Y1 = fminf(fmaxf(Y1, 0.f), Hf);
        X2 = fminf(fmaxf(X2, 0.f), Wf); Y2 = fminf(fmaxf(Y2, 0.f), Hf);
        boxes[4 * r] = X1; boxes[4 * r + 1] = Y1; boxes[4 * r + 2] = X2; boxes[4 * r + 3] = Y2;
        valid[r] = ((X2 - X1) >= 1.0f && (Y2 - Y1) >= 1.0f) ? 1 : 0;
    }
}

// ---- NMS IoU bitmask: mask[i][jw] bit b = (j=jw*64+b > i) && iou>0.7 ----
__global__ __launch_bounds__(256) void k_mask(const float* __restrict__ boxes,
                                              unsigned long long* __restrict__ mask) {
    __shared__ float jb[256];
    int jw = blockIdx.x;
    int i = blockIdx.y * 256 + threadIdx.x;
    {
        int idx = jw * 256 + threadIdx.x;
        jb[threadIdx.x] = (idx < PRE_N * 4) ? boxes[idx] : 0.f;
    }
    __syncthreads();
    if (i >= PRE_N) return;
    float ax1 = boxes[4 * i], ay1 = boxes[4 * i + 1], ax2 = boxes[4 * i + 2], ay2 = boxes[4 * i + 3];
    float aarea = (ax2 - ax1) * (ay2 - ay1);
    unsigned long long m = 0;
    int jbase = jw * 64;
    for (int b = 0; b < 64; b++) {
        int j = jbase + b;
        if (j <= i || j >= PRE_N) continue;
        float bx1 = jb[4 * b], by1 = jb[4 * b + 1], bx2 = jb[4 * b + 2], by2 = jb[4 * b + 3];
        float barea = (bx2 - bx1) * (by2 - by1);
        float xx1 = fmaxf(ax1, bx1), yy1 = fmaxf(ay1, by1);
        float xx2 = fminf(ax2, bx2), yy2 = fminf(ay2, by2);
        float w = fmaxf(xx2 - xx1, 0.f), h = fmaxf(yy2 - yy1, 0.f);
        float inter = w * h;
        float iou = inter / (aarea + barea - inter + 1e-9f);
        if (iou > 0.7f) m |= (1ull << b);
    }
    mask[(size_t)i * NWORDS + jw] = m;
}

// ---- greedy scan: diagonal masks preloaded to LDS; serial part iterates kept bits ----
__global__ __launch_bounds__(128) void k_scan_nms(const unsigned long long* __restrict__ mask,
                                                  const int* __restrict__ valid,
                                                  const float* __restrict__ boxes,
                                                  float* __restrict__ out) {
    __shared__ unsigned long long diag[NWORDS][64];   // 48,128 B
    __shared__ unsigned long long removed[NWORDS];
    __shared__ unsigned long long validw[NWORDS];
    __shared__ int keepList[POST_N];
    __shared__ int cnt;
    __shared__ unsigned long long keptbits;
    int t = threadIdx.x;
    if (t < NWORDS) { removed[t] = 0ull; validw[t] = 0ull; }
    if (t == 0) cnt = 0;
    __syncthreads();
    for (int l = t; l < NWORDS * 64; l += 128) {
        int w = l >> 6, b = l & 63;
        int i = w * 64 + b;
        diag[w][b] = (i < PRE_N) ? mask[(size_t)i * NWORDS + w] : 0ull;
    }
    for (int i = t; i < PRE_N; i += 128)
        if (valid[i]) atomicOr(&validw[i >> 6], 1ull << (i & 63));
    __syncthreads();
    for (int w = 0; w < NWORDS; w++) {
        unsigned long long candw = validw[w] & ~removed[w];
        if (!candw) continue;
        if (t == 0) {
            unsigned long long cand = candw;
            unsigned long long kb = 0ull;
            int c = cnt;
            while (cand && c < POST_N) {
                int b = __ffsll((unsigned long long)cand) - 1;
                keepList[c++] = w * 64 + b;
                kb |= 1ull << b;
                cand &= ~(1ull << b);
                cand &= ~diag[w][b];
            }
            cnt = c; keptbits = kb;
        }
        __syncthreads();
        if (cnt >= POST_N) break;
        unsigned long long kb = keptbits;
        if (kb) {
            for (int w2 = w + 1 + t; w2 < NWORDS; w2 += 128) {
                unsigned long long acc2 = removed[w2];
                unsigned long long tt = kb;
                while (tt) {
                    int b = __ffsll((unsigned long long)tt) - 1;
                    tt &= tt - 1;
                    acc2 |= mask[(size_t)(w * 64 + b) * NWORDS + w2];
                }
                removed[w2] = acc2;
            }
        }
        __syncthreads();
    }
    __syncthreads();
    int c = cnt;
    for (int e = t; e < POST_N * 4; e += 128) {
        int r = e >> 2;
        out[e] = (r < c) ? boxes[4 * keepList[r] + (e & 3)] : 0.f;
    }
}

extern "C" void kernel_launch(void* const* d_in, const int* in_sizes, int n_in,
                              void* d_out, int out_size, void* d_ws, size_t ws_size,
                              hipStream_t stream) {
    const float* feature = (const float*)d_in[0];
    const float* w1   = (const float*)d_in[1];
    const float* b1   = (const float*)d_in[2];
    const float* wcls = (const float*)d_in[3];
    const float* bcls = (const float*)d_in[4];
    const float* wreg = (const float*)d_in[5];
    const float* breg = (const float*)d_in[6];
    const int* imh = (const int*)d_in[7];
    const int* imw = (const int*)d_in[8];

    char* ws = (char*)d_ws;
    float* xbuf  = (float*)(ws + X_OFF);
    float* conf  = (float*)(ws + CONF_OFF);
    unsigned* hist1 = (unsigned*)(ws + HIST1_OFF);
    unsigned* scal  = (unsigned*)(ws + SCAL_OFF);
    unsigned long long* sel = (unsigned long long*)(ws + SEL_OFF);
    unsigned* topidx = (unsigned*)(ws + TOPIDX_OFF);
    float* boxes = (float*)(ws + BOXES_OFF);
    int* valid   = (int*)(ws + VALID_OFF);
    unsigned long long* mask = (unsigned long long*)(ws + MASK_OFF);
    float* wcr = (float*)(ws + WCR_OFF);
    float* outF = (float*)d_out;

    hipLaunchKernelGGL(k_conv1,  dim3(9, 25, 8), dim3(256), 0, stream,
                       feature, w1, b1, xbuf, hist1, scal, sel, wcls, wcr);
    hipLaunchKernelGGL(k_cls,    dim3(213),  dim3(256), 0, stream, xbuf, wcr, bcls, conf, hist1);
    hipLaunchKernelGGL(k_scan,   dim3(1),    dim3(1024), 0, stream, hist1, scal);
    hipLaunchKernelGGL(k_gather, dim3(1913), dim3(256), 0, stream, conf, scal, sel);
    hipLaunchKernelGGL(k_rank,   dim3(64),   dim3(256), 0, stream, scal, sel, topidx);
    hipLaunchKernelGGL(k_prop,   dim3(PRE_N), dim3(64), 0, stream, xbuf, wreg, breg, topidx, imh, imw, boxes, valid);
    hipLaunchKernelGGL(k_mask,   dim3(NWORDS, 24), dim3(256), 0, stream, boxes, mask);
    hipLaunchKernelGGL(k_scan_nms, dim3(1), dim3(128), 0, stream, mask, valid, boxes, outF);
}